// Round 9
// baseline (102.872 us; speedup 1.0000x reference)
//
#include <hip/hip_runtime.h>

#define N_SAMPLES 131072
#define N_FEAT    512
#define N_PAIRS   (N_SAMPLES / 2)
#define N_KER     29
#define PAIR_F    (2 * N_FEAT)   // floats per pair (two adjacent rows)
#define MAX_NB    2048           // retry full residency now that nt moved the wall

// Native vector type: __builtin_nontemporal_load rejects HIP_vector_type
// (class), but accepts ext_vector_type (R7 compile lesson).
typedef float v4f __attribute__((ext_vector_type(4)));

// 8 x v4f = 32 VGPRs of loaded data per pipeline stage.
struct Batch {
  v4f x0, x1, xp0, xp1, y0, y1, yp0, yp1;
};

// Non-temporal 16B load: global_load_dwordx4 'nt' (streaming, evict-first).
// R8 measured: relieves the per-XCD L2 allocation wall, 107.7 -> 94.7 us.
__device__ __forceinline__ v4f ldnt(const float* p) {
  return __builtin_nontemporal_load(reinterpret_cast<const v4f*>(p));
}

__device__ __forceinline__ void load_batch(const float* __restrict__ Xs,
                                           const float* __restrict__ Xt,
                                           int p, int o0, Batch& b) {
  const float* x = Xs + (size_t)p * PAIR_F;
  const float* y = Xt + (size_t)p * PAIR_F;
  b.x0  = ldnt(x + o0);
  b.x1  = ldnt(x + o0 + 256);
  b.xp0 = ldnt(x + o0 + N_FEAT);
  b.xp1 = ldnt(x + o0 + N_FEAT + 256);
  b.y0  = ldnt(y + o0);
  b.y1  = ldnt(y + o0 + 256);
  b.yp0 = ldnt(y + o0 + N_FEAT);
  b.yp1 = ldnt(y + o0 + N_FEAT + 256);
}

__device__ __forceinline__ void compute_pair(const Batch& b, double c, int lane,
                                             double& acc) {
  double d0 = 0.0, d1 = 0.0, d2 = 0.0, d3 = 0.0;

#define MMD_ACC(A, AP, B, BP)                                   \
  {                                                             \
    const double ax  = (double)(A);                             \
    const double axp = (double)(AP);                            \
    const double ay  = (double)(B);                             \
    const double ayp = (double)(BP);                            \
    double t;                                                   \
    t = ax - axp; d0 = fma(t, t, d0);                           \
    t = ay - ayp; d1 = fma(t, t, d1);                           \
    t = ax - ayp; d2 = fma(t, t, d2);                           \
    t = axp - ay; d3 = fma(t, t, d3);                           \
  }
  MMD_ACC(b.x0.x, b.xp0.x, b.y0.x, b.yp0.x)
  MMD_ACC(b.x0.y, b.xp0.y, b.y0.y, b.yp0.y)
  MMD_ACC(b.x0.z, b.xp0.z, b.y0.z, b.yp0.z)
  MMD_ACC(b.x0.w, b.xp0.w, b.y0.w, b.yp0.w)
  MMD_ACC(b.x1.x, b.xp1.x, b.y1.x, b.yp1.x)
  MMD_ACC(b.x1.y, b.xp1.y, b.y1.y, b.yp1.y)
  MMD_ACC(b.x1.z, b.xp1.z, b.y1.z, b.yp1.z)
  MMD_ACC(b.x1.w, b.xp1.w, b.y1.w, b.yp1.w)
#undef MMD_ACC

  // butterfly reduce across 64 lanes (result broadcast to all lanes)
#pragma unroll
  for (int s = 32; s > 0; s >>= 1) {
    d0 += __shfl_xor(d0, s);
    d1 += __shfl_xor(d1, s);
    d2 += __shfl_xor(d2, s);
    d3 += __shfl_xor(d3, s);
  }

  if (lane < N_KER) {
    acc += exp(-d0 * c) + exp(-d1 * c) - exp(-d2 * c) - exp(-d3 * c);
  }
}

// Kernel 1: depth-2 pipeline, strided round-robin sweep, nt loads.
__global__ __launch_bounds__(256) void mmd_partial(
    const float* __restrict__ Xs, const float* __restrict__ Xt,
    double* __restrict__ ws, int nwaves) {
  const int tid  = threadIdx.x;
  const int lane = tid & 63;
  const int wib  = tid >> 6;
  const int gw   = blockIdx.x * 4 + wib;
  const int o0   = lane * 4;

  const double c = exp2(6.0 - 0.5 * (double)lane);  // 1/(2*gamma_g^2), exact
  double acc = 0.0;

  int p = gw;
  if (p < N_PAIRS) {
    Batch A, B;
    load_batch(Xs, Xt, p, o0, A);
    int pn = p + nwaves;
    bool pendingA = true;
    while (pn < N_PAIRS) {
      load_batch(Xs, Xt, pn, o0, B);
      compute_pair(A, c, lane, acc);
      pn += nwaves;
      if (pn < N_PAIRS) {
        load_batch(Xs, Xt, pn, o0, A);
        compute_pair(B, c, lane, acc);
        pn += nwaves;
      } else {
        compute_pair(B, c, lane, acc);
        pendingA = false;
        break;
      }
    }
    if (pendingA) compute_pair(A, c, lane, acc);
  }

  // block reduction: 4 waves -> 32 padded doubles
  __shared__ double sacc[4][32];
  if (lane < 32) sacc[wib][lane] = (lane < N_KER) ? acc : 0.0;
  __syncthreads();
  if (tid < 32) {
    const double s = sacc[0][tid] + sacc[1][tid] + sacc[2][tid] + sacc[3][tid];
    ws[(size_t)blockIdx.x * 32 + tid] = s;
  }
}

// Kernel 2: deterministic reduction over block partials; fold betas; mean.
__global__ __launch_bounds__(1024) void mmd_final(
    const double* __restrict__ ws, const float* __restrict__ betas,
    float* __restrict__ out, int nb) {
  const int tid = threadIdx.x;
  double acc = 0.0;
  const int total = nb * 32;
  for (int i = tid; i < total; i += 1024) {
    const int g = i & 31;
    if (g < N_KER) acc += (double)betas[g] * ws[i];
  }
  __shared__ double s[1024];
  s[tid] = acc;
  __syncthreads();
  for (int ofs = 512; ofs > 0; ofs >>= 1) {
    if (tid < ofs) s[tid] += s[tid + ofs];
    __syncthreads();
  }
  if (tid == 0) out[0] = (float)(s[0] / (double)N_PAIRS);
}

extern "C" void kernel_launch(void* const* d_in, const int* in_sizes, int n_in,
                              void* d_out, int out_size, void* d_ws, size_t ws_size,
                              hipStream_t stream) {
  const float* Xs    = (const float*)d_in[0];
  const float* Xt    = (const float*)d_in[1];
  const float* betas = (const float*)d_in[2];
  float*  out = (float*)d_out;
  double* ws  = (double*)d_ws;

  // Largest power-of-two block count that fits ws (32 doubles per block),
  // capped at MAX_NB (=2048: exactly fills 256 CU x 32 waves).
  size_t nb_fit = ws_size / (32 * sizeof(double));
  int nb = 1;
  while ((size_t)(nb * 2) <= nb_fit && nb * 2 <= MAX_NB) nb *= 2;

  mmd_partial<<<nb, 256, 0, stream>>>(Xs, Xt, ws, nb * 4);
  mmd_final<<<1, 1024, 0, stream>>>(ws, betas, out, nb);
}

// Round 10
// 93.437 us; speedup vs baseline: 1.1010x; 1.1010x over previous
//
#include <hip/hip_runtime.h>

#define N_SAMPLES 131072
#define N_FEAT    512
#define N_PAIRS   (N_SAMPLES / 2)
#define N_KER     29
#define PAIR_F    (2 * N_FEAT)   // floats per pair (two adjacent rows)
#define MAX_NB    1024           // best measured (R8: 94.7 us); 2048 regressed (R9)

// Native vector type: __builtin_nontemporal_load rejects HIP_vector_type
// (class), but accepts ext_vector_type (R7 compile lesson).
typedef float v4f __attribute__((ext_vector_type(4)));

// 8 x v4f = 32 VGPRs of loaded data per pipeline stage.
struct Batch {
  v4f x0, x1, xp0, xp1, y0, y1, yp0, yp1;
};

// Non-temporal 16B load: global_load_dwordx4 'nt' (streaming, evict-first).
// R8 measured: relieves the per-XCD L2 allocation wall, 107.7 -> 94.7 us
// (combined L3+HBM service ~4.9 -> ~5.75 TB/s, 91% of copy ceiling).
__device__ __forceinline__ v4f ldnt(const float* p) {
  return __builtin_nontemporal_load(reinterpret_cast<const v4f*>(p));
}

__device__ __forceinline__ void load_batch(const float* __restrict__ Xs,
                                           const float* __restrict__ Xt,
                                           int p, int o0, Batch& b) {
  const float* x = Xs + (size_t)p * PAIR_F;
  const float* y = Xt + (size_t)p * PAIR_F;
  b.x0  = ldnt(x + o0);
  b.x1  = ldnt(x + o0 + 256);
  b.xp0 = ldnt(x + o0 + N_FEAT);
  b.xp1 = ldnt(x + o0 + N_FEAT + 256);
  b.y0  = ldnt(y + o0);
  b.y1  = ldnt(y + o0 + 256);
  b.yp0 = ldnt(y + o0 + N_FEAT);
  b.yp1 = ldnt(y + o0 + N_FEAT + 256);
}

__device__ __forceinline__ void compute_pair(const Batch& b, double c, int lane,
                                             double& acc) {
  double d0 = 0.0, d1 = 0.0, d2 = 0.0, d3 = 0.0;

#define MMD_ACC(A, AP, B, BP)                                   \
  {                                                             \
    const double ax  = (double)(A);                             \
    const double axp = (double)(AP);                            \
    const double ay  = (double)(B);                             \
    const double ayp = (double)(BP);                            \
    double t;                                                   \
    t = ax - axp; d0 = fma(t, t, d0);                           \
    t = ay - ayp; d1 = fma(t, t, d1);                           \
    t = ax - ayp; d2 = fma(t, t, d2);                           \
    t = axp - ay; d3 = fma(t, t, d3);                           \
  }
  MMD_ACC(b.x0.x, b.xp0.x, b.y0.x, b.yp0.x)
  MMD_ACC(b.x0.y, b.xp0.y, b.y0.y, b.yp0.y)
  MMD_ACC(b.x0.z, b.xp0.z, b.y0.z, b.yp0.z)
  MMD_ACC(b.x0.w, b.xp0.w, b.y0.w, b.yp0.w)
  MMD_ACC(b.x1.x, b.xp1.x, b.y1.x, b.yp1.x)
  MMD_ACC(b.x1.y, b.xp1.y, b.y1.y, b.yp1.y)
  MMD_ACC(b.x1.z, b.xp1.z, b.y1.z, b.yp1.z)
  MMD_ACC(b.x1.w, b.xp1.w, b.y1.w, b.yp1.w)
#undef MMD_ACC

  // butterfly reduce across 64 lanes (result broadcast to all lanes)
#pragma unroll
  for (int s = 32; s > 0; s >>= 1) {
    d0 += __shfl_xor(d0, s);
    d1 += __shfl_xor(d1, s);
    d2 += __shfl_xor(d2, s);
    d3 += __shfl_xor(d3, s);
  }

  if (lane < N_KER) {
    acc += exp(-d0 * c) + exp(-d1 * c) - exp(-d2 * c) - exp(-d3 * c);
  }
}

// Kernel 1: depth-2 pipeline, strided round-robin sweep, nt loads.
__global__ __launch_bounds__(256) void mmd_partial(
    const float* __restrict__ Xs, const float* __restrict__ Xt,
    double* __restrict__ ws, int nwaves) {
  const int tid  = threadIdx.x;
  const int lane = tid & 63;
  const int wib  = tid >> 6;
  const int gw   = blockIdx.x * 4 + wib;
  const int o0   = lane * 4;

  const double c = exp2(6.0 - 0.5 * (double)lane);  // 1/(2*gamma_g^2), exact
  double acc = 0.0;

  int p = gw;
  if (p < N_PAIRS) {
    Batch A, B;
    load_batch(Xs, Xt, p, o0, A);
    int pn = p + nwaves;
    bool pendingA = true;
    while (pn < N_PAIRS) {
      load_batch(Xs, Xt, pn, o0, B);
      compute_pair(A, c, lane, acc);
      pn += nwaves;
      if (pn < N_PAIRS) {
        load_batch(Xs, Xt, pn, o0, A);
        compute_pair(B, c, lane, acc);
        pn += nwaves;
      } else {
        compute_pair(B, c, lane, acc);
        pendingA = false;
        break;
      }
    }
    if (pendingA) compute_pair(A, c, lane, acc);
  }

  // block reduction: 4 waves -> 32 padded doubles
  __shared__ double sacc[4][32];
  if (lane < 32) sacc[wib][lane] = (lane < N_KER) ? acc : 0.0;
  __syncthreads();
  if (tid < 32) {
    const double s = sacc[0][tid] + sacc[1][tid] + sacc[2][tid] + sacc[3][tid];
    ws[(size_t)blockIdx.x * 32 + tid] = s;
  }
}

// Kernel 2: deterministic reduction over block partials; fold betas; mean.
__global__ __launch_bounds__(1024) void mmd_final(
    const double* __restrict__ ws, const float* __restrict__ betas,
    float* __restrict__ out, int nb) {
  const int tid = threadIdx.x;
  double acc = 0.0;
  const int total = nb * 32;
  for (int i = tid; i < total; i += 1024) {
    const int g = i & 31;
    if (g < N_KER) acc += (double)betas[g] * ws[i];
  }
  __shared__ double s[1024];
  s[tid] = acc;
  __syncthreads();
  for (int ofs = 512; ofs > 0; ofs >>= 1) {
    if (tid < ofs) s[tid] += s[tid + ofs];
    __syncthreads();
  }
  if (tid == 0) out[0] = (float)(s[0] / (double)N_PAIRS);
}

extern "C" void kernel_launch(void* const* d_in, const int* in_sizes, int n_in,
                              void* d_out, int out_size, void* d_ws, size_t ws_size,
                              hipStream_t stream) {
  const float* Xs    = (const float*)d_in[0];
  const float* Xt    = (const float*)d_in[1];
  const float* betas = (const float*)d_in[2];
  float*  out = (float*)d_out;
  double* ws  = (double*)d_ws;

  // Largest power-of-two block count that fits ws (32 doubles per block).
  size_t nb_fit = ws_size / (32 * sizeof(double));
  int nb = 1;
  while ((size_t)(nb * 2) <= nb_fit && nb * 2 <= MAX_NB) nb *= 2;

  mmd_partial<<<nb, 256, 0, stream>>>(Xs, Xt, ws, nb * 4);
  mmd_final<<<1, 1024, 0, stream>>>(ws, betas, out, nb);
}